// Round 10
// baseline (325.802 us; speedup 1.0000x reference)
//
#include <hip/hip_runtime.h>
#include <math.h>

#define HH 512
#define WW 512
#define HWp (HH * WW)
#define TT 5
#define CC 5

// conv tiling: 64 x 16 tile, 512 threads, 1 col x 2 adjacent rows per thread
#define CTW 64
#define CTH 16
#define NROW (CTH + 2)        // 18
#define GCOL 18               // 16B granules per padded row: cols [gcol0-4, gcol0+68)
#define LCP (GCOL * 4)        // 72 floats per padded row (granule g <-> byte g*16, linear)
#define LDSF (CC * NROW * LCP)   // 6480 floats = 25920 B per buffer
#define NG (CC * NROW * GCOL)    // 1620 granules
#define NBUF 2
#define SPARE_BYTES (NBUF * LDSF * 4)   // dump slot for dummy loads

#define NHEADB 84             // 672 head waves / 8 waves-per-block
#define NCONVB 2048           // 8 x 32 x 8

typedef float v2f __attribute__((ext_vector_type(2)));

typedef __attribute__((address_space(3))) char       lds_char_t;
typedef __attribute__((address_space(1)))  const char glb_char_t;

__device__ __forceinline__ float fast_sigmoid(float x) {
    return __builtin_amdgcn_rcpf(1.0f + __expf(-x));
}

// ---------------- head: one wave owns 64 pixels, all channels ----------------
template<int CIN, int F, int LGF>
__device__ __forceinline__ void head_wave(const float* __restrict__ y,
                                          const float* __restrict__ w,
                                          const float* __restrict__ bias,
                                          float* __restrict__ det,
                                          int b, int chunk, int lane,
                                          float scale, int row_off,
                                          float aw0, float ah0, float aw1, float ah1,
                                          float aw2, float ah2)
{
    const int n   = F * F;
    const int pix = chunk * 64 + lane;

    float acc[21];
    #pragma unroll
    for (int o = 0; o < 21; ++o) acc[o] = bias[o];

    const float* yp = y + (size_t)b * CIN * n + pix;
    for (int c = 0; c < CIN; ++c) {
        float v = yp[(size_t)c * n];              // coalesced across lanes
        #pragma unroll
        for (int o = 0; o < 21; ++o)
            acc[o] = fmaf(v, w[o * CIN + c], acc[o]);   // uniform -> s_load
    }

    const int hy = pix >> LGF;
    const int hx = pix & (F - 1);
    const float inv = 1.0f / 512.0f;
    const float AW[3] = {aw0, aw1, aw2};
    const float AH[3] = {ah0, ah1, ah2};

    #pragma unroll
    for (int a = 0; a < 3; ++a) {
        const int row = row_off + pix * 3 + a;
        float* dp = det + ((size_t)b * 16128 + row) * 7;
        dp[0] = acc[a];
        dp[1] = acc[3 + a * 2];
        dp[2] = acc[4 + a * 2];
        float cx = (fast_sigmoid(acc[9  + a * 4]) + (float)hx) * scale;
        float cy = (fast_sigmoid(acc[10 + a * 4]) + (float)hy) * scale;
        float bw = __expf(acc[11 + a * 4]) * AW[a];
        float bh = __expf(acc[12 + a * 4]) * AH[a];
        dp[3] = (cx - bw * 0.5f) * inv;
        dp[4] = (cy - bh * 0.5f) * inv;
        dp[5] = (cx + bw * 0.5f) * inv;
        dp[6] = (cy + bh * 0.5f) * inv;
    }
}

extern "C" __global__ __launch_bounds__(512, 6)
void spikefpn_fused(const float* __restrict__ x, const float* __restrict__ cw,
                    const float* __restrict__ gamma, const float* __restrict__ beta,
                    const float* __restrict__ cm, const float* __restrict__ vleak,
                    const float* __restrict__ tau, const float* __restrict__ erev,
                    const float* __restrict__ y3, const float* __restrict__ w3, const float* __restrict__ b3,
                    const float* __restrict__ y2, const float* __restrict__ w2, const float* __restrict__ b2,
                    const float* __restrict__ y1, const float* __restrict__ w1, const float* __restrict__ b1,
                    float* __restrict__ out, float* __restrict__ det)
{
    __shared__ float xs[NBUF * LDSF + 256];

    const int bid = blockIdx.x;
    const int tid = threadIdx.x;

    if (bid < NHEADB) {
        // ---------------- head path: wave-independent, no sync ----------------
        const int wid  = bid * 8 + (tid >> 6);   // 0..671
        const int lane = tid & 63;
        if (wid < 512) {
            head_wave<192, 64, 6>(y3, w3, b3, det, wid >> 6, wid & 63, lane,
                                  8.0f, 0, 10.f, 13.f, 16.f, 30.f, 33.f, 23.f);
        } else if (wid < 640) {
            const int sb = wid - 512;
            head_wave<384, 32, 5>(y2, w2, b2, det, sb >> 4, sb & 15, lane,
                                  16.0f, 12288, 30.f, 61.f, 62.f, 45.f, 59.f, 119.f);
        } else {
            const int sb = wid - 640;
            head_wave<768, 16, 4>(y1, w1, b1, det, sb >> 2, sb & 3, lane,
                                  32.0f, 15360, 116.f, 90.f, 156.f, 198.f, 373.f, 326.f);
        }
        return;
    }

    // ---------------- conv + LTC: global_load_lds, NBUF=2, counted waits ----------------
    const int cb = bid - NHEADB;
    const int bx = cb & 7;            // col tile 0..7
    const int by = (cb >> 3) & 31;    // row tile 0..31
    const int b  = cb >> 8;           // batch

    const int grow0 = by * CTH;
    const int gcol0 = bx * CTW;
    const size_t xb = (size_t)b * (TT * CC * HWp);

    // ---- per-thread staging meta (once). Every wave issues EXACTLY 4 loads/stage.
    int  goff[4];
    bool pred[4];
    uint32_t gbase[4];
    #pragma unroll
    for (int k = 0; k < 4; ++k) {
        const int g = tid + k * 512;
        const int wavebase = (tid & ~63) + k * 512;
        if (wavebase >= NG) {
            pred[k] = true;
            goff[k] = 0;
            gbase[k] = (uint32_t)SPARE_BYTES;
        } else {
            const bool valid = g < NG;
            const int gg  = valid ? g : 0;
            const int ch  = gg / (NROW * GCOL);
            const int rem = gg - ch * (NROW * GCOL);
            const int row = rem / GCOL;
            const int c4  = rem - row * GCOL;
            const int gr = grow0 + row - 1;
            const int gc = gcol0 - 4 + c4 * 4;
            const bool inb = valid && ((unsigned)gr < (unsigned)HH) && ((unsigned)gc < (unsigned)WW);
            pred[k] = inb;
            goff[k] = ch * HWp + gr * WW + gc;
            gbase[k] = (uint32_t)(wavebase * 16);   // wave-uniform LDS base
            if (valid && !inb) {
                float4 z = make_float4(0.f, 0.f, 0.f, 0.f);
                *(float4*)&xs[g * 4]        = z;
                *(float4*)&xs[LDSF + g * 4] = z;
            }
        }
    }

    lds_char_t* lds0 = (lds_char_t*)xs;

    auto issue_stage = [&](int t, int buf) {
        const float* xt = x + xb + (size_t)t * (CC * HWp);
        const uint32_t bufoff = (uint32_t)buf * (LDSF * 4);
        #pragma unroll
        for (int k = 0; k < 4; ++k) {
            if (pred[k]) {
                __builtin_amdgcn_global_load_lds(
                    (const __attribute__((address_space(1))) void*)(glb_char_t*)(const char*)(xt + goff[k]),
                    (__attribute__((address_space(3))) void*)(lds0 + bufoff + gbase[k]),
                    16, 0, 0);
            }
        }
    };

    // per-channel params + exp2-folded constants (uniform -> SGPR)
    const float L2E = 1.442695040888963f;
    float g_[CC], be[CC], cmv[CC], vl[CC], gL[CC], bL[CC], tmL[CC], erL[CC];
    #pragma unroll
    for (int o = 0; o < CC; ++o) {
        g_[o] = gamma[o]; be[o] = beta[o]; cmv[o] = cm[o]; vl[o] = vleak[o];
        gL[o]  = -g_[o] * L2E;
        bL[o]  = -be[o] * L2E;
        tmL[o] = -tau[o] * L2E;
        erL[o] = -erev[o] * L2E;
    }

    const int tx = tid & 63;          // col 0..63
    const int r0 = (tid >> 6) * 2;    // rows r0, r0+1 (wave-uniform)

    // ---- prologue: stage t0 -> buf0, drain (covers zero-fills too) ----
    issue_stage(0, 0);
    asm volatile("s_waitcnt vmcnt(0)" ::: "memory");
    asm volatile("s_waitcnt lgkmcnt(0)" ::: "memory");
    __builtin_amdgcn_s_barrier();
    __builtin_amdgcn_sched_barrier(0);

    v2f vpre[CC];   // .x = row r0, .y = row r0+1
    #pragma unroll
    for (int o = 0; o < CC; ++o) vpre[o] = (v2f){0.0f, 0.0f};

    #pragma unroll
    for (int t = 0; t < TT; ++t) {
        if (t + 1 < TT) issue_stage(t + 1, (t + 1) & 1);   // 1-deep prefetch

        const float* cur = xs + (t & 1) * LDSF;

        v2f acc[CC];
        #pragma unroll
        for (int o = 0; o < CC; ++o) acc[o] = (v2f){0.0f, 0.0f};

        #pragma unroll
        for (int ic = 0; ic < CC; ++ic) {
            // pairs (row r0+dr, row r0+dr+1) at cols tx..tx+2 -> ds_read2_b32 (72 dw apart)
            const float* lp = &cur[(ic * NROW + r0) * LCP + tx + 3];
            v2f xv[3][3];
            #pragma unroll
            for (int dr = 0; dr < 3; ++dr)
                #pragma unroll
                for (int dc = 0; dc < 3; ++dc)
                    xv[dr][dc] = (v2f){lp[dr * LCP + dc], lp[(dr + 1) * LCP + dc]};
            #pragma unroll
            for (int oc = 0; oc < CC; ++oc) {
                const float* wp = cw + (oc * CC + ic) * 9;   // uniform -> s_load (lgkmcnt)
                v2f a = acc[oc];
                #pragma unroll
                for (int dr = 0; dr < 3; ++dr)
                    #pragma unroll
                    for (int dc = 0; dc < 3; ++dc) {
                        const float w = wp[dr * 3 + dc];
                        a = __builtin_elementwise_fma((v2f){w, w}, xv[dr][dc], a);
                    }
                acc[oc] = a;
            }
        }

        // ---- LTC update (exp2-folded) + store (2 rows x 5 ch = 10 b32 stores) ----
        const size_t ob0 = (size_t)(grow0 + r0) * WW + gcol0 + tx;
        #pragma unroll
        for (int o = 0; o < CC; ++o) {
            float* op = out + ((size_t)((b * TT + t) * CC + o)) * HWp + ob0;

            v2f a    = acc[o];
            v2f wih  = __builtin_elementwise_fma(a, (v2f){g_[o], g_[o]}, (v2f){be[o], be[o]});
            v2f targ = __builtin_elementwise_fma(a, (v2f){gL[o], gL[o]}, (v2f){bL[o], bL[o]});
            float sg0 = __builtin_amdgcn_rcpf(1.0f + __builtin_amdgcn_exp2f(targ.x));
            float sg1 = __builtin_amdgcn_rcpf(1.0f + __builtin_amdgcn_exp2f(targ.y));
            float rd0 = __builtin_amdgcn_rcpf(fmaf(cmv[o], sg0, vl[o]));
            float rd1 = __builtin_amdgcn_rcpf(fmaf(cmv[o], sg1, vl[o]));
            v2f tv = vpre[o] * (v2f){tmL[o], tmL[o]};
            v2f we = wih * (v2f){erL[o], erL[o]};
            float va0 = fmaf(tv.x, rd0, we.x);
            float va1 = fmaf(tv.y, rd1, we.y);
            float v0 = __builtin_amdgcn_rcpf(1.0f + __builtin_amdgcn_exp2f(va0));
            float v1 = __builtin_amdgcn_rcpf(1.0f + __builtin_amdgcn_exp2f(va1));
            vpre[o] = (v2f){v0, v1};
            op[0]  = v0;
            op[WW] = v1;
        }

        // ---- counted wait: stores(t) are the 10 youngest; S(t+1) retired at vmcnt(10) ----
        if (t < TT - 1) {
            asm volatile("s_waitcnt vmcnt(10)" ::: "memory");
            __builtin_amdgcn_s_barrier();
            __builtin_amdgcn_sched_barrier(0);
        }
    }
}

extern "C" void kernel_launch(void* const* d_in, const int* in_sizes, int n_in,
                              void* d_out, int out_size, void* d_ws, size_t ws_size,
                              hipStream_t stream)
{
    const float* x     = (const float*)d_in[0];
    const float* y1    = (const float*)d_in[1];   // [8,768,16,16]
    const float* y2    = (const float*)d_in[2];   // [8,384,32,32]
    const float* y3    = (const float*)d_in[3];   // [8,192,64,64]
    const float* cw    = (const float*)d_in[4];
    const float* gamma = (const float*)d_in[5];
    const float* beta  = (const float*)d_in[6];
    const float* cm    = (const float*)d_in[7];
    const float* vleak = (const float*)d_in[8];
    const float* tau   = (const float*)d_in[9];
    const float* erev  = (const float*)d_in[10];
    const float* w1    = (const float*)d_in[11];
    const float* b1    = (const float*)d_in[12];
    const float* w2    = (const float*)d_in[13];
    const float* b2    = (const float*)d_in[14];
    const float* w3    = (const float*)d_in[15];
    const float* b3    = (const float*)d_in[16];

    float* out = (float*)d_out;
    float* det = out + (size_t)8 * TT * CC * HH * WW;   // 52,428,800

    spikefpn_fused<<<dim3(NHEADB + NCONVB), 512, 0, stream>>>(
        x, cw, gamma, beta, cm, vleak, tau, erev,
        y3, w3, b3, y2, w2, b2, y1, w1, b1, out, det);
}

// Round 11
// 261.331 us; speedup vs baseline: 1.2467x; 1.2467x over previous
//
#include <hip/hip_runtime.h>
#include <math.h>

#define HH 512
#define WW 512
#define HWp (HH * WW)
#define TT 5
#define CC 5

// conv tiling: 64 x 16 tile, 512 threads, 1 col x 2 adjacent rows per thread
#define CTW 64
#define CTH 16
#define NROW (CTH + 2)        // 18
#define GCOL 18               // 16B granules per padded row: cols [gcol0-4, gcol0+68)
#define LCP (GCOL * 4)        // 72 floats per padded row (granule g <-> byte g*16, linear)
#define LDSF (CC * NROW * LCP)   // 6480 floats = 25920 B per buffer
#define NG (CC * NROW * GCOL)    // 1620 granules
#define NBUF 2
#define SPARE_BYTES (NBUF * LDSF * 4)   // dump slot for dummy loads

#define NHEADB 84             // 672 head waves / 8 waves-per-block
#define NCONVB 2048           // 8 x 32 x 8

typedef float v2f __attribute__((ext_vector_type(2)));

typedef __attribute__((address_space(3))) char       lds_char_t;
typedef __attribute__((address_space(1)))  const char glb_char_t;

__device__ __forceinline__ float fast_sigmoid(float x) {
    return __builtin_amdgcn_rcpf(1.0f + __expf(-x));
}

// ---------------- head: one wave owns 64 pixels, all channels ----------------
template<int CIN, int F, int LGF>
__device__ __forceinline__ void head_wave(const float* __restrict__ y,
                                          const float* __restrict__ w,
                                          const float* __restrict__ bias,
                                          float* __restrict__ det,
                                          int b, int chunk, int lane,
                                          float scale, int row_off,
                                          float aw0, float ah0, float aw1, float ah1,
                                          float aw2, float ah2)
{
    const int n   = F * F;
    const int pix = chunk * 64 + lane;

    float acc[21];
    #pragma unroll
    for (int o = 0; o < 21; ++o) acc[o] = bias[o];

    const float* yp = y + (size_t)b * CIN * n + pix;
    for (int c = 0; c < CIN; ++c) {
        float v = yp[(size_t)c * n];              // coalesced across lanes
        #pragma unroll
        for (int o = 0; o < 21; ++o)
            acc[o] = fmaf(v, w[o * CIN + c], acc[o]);   // uniform -> s_load
    }

    const int hy = pix >> LGF;
    const int hx = pix & (F - 1);
    const float inv = 1.0f / 512.0f;
    const float AW[3] = {aw0, aw1, aw2};
    const float AH[3] = {ah0, ah1, ah2};

    #pragma unroll
    for (int a = 0; a < 3; ++a) {
        const int row = row_off + pix * 3 + a;
        float* dp = det + ((size_t)b * 16128 + row) * 7;
        dp[0] = acc[a];
        dp[1] = acc[3 + a * 2];
        dp[2] = acc[4 + a * 2];
        float cx = (fast_sigmoid(acc[9  + a * 4]) + (float)hx) * scale;
        float cy = (fast_sigmoid(acc[10 + a * 4]) + (float)hy) * scale;
        float bw = __expf(acc[11 + a * 4]) * AW[a];
        float bh = __expf(acc[12 + a * 4]) * AH[a];
        dp[3] = (cx - bw * 0.5f) * inv;
        dp[4] = (cy - bh * 0.5f) * inv;
        dp[5] = (cx + bw * 0.5f) * inv;
        dp[6] = (cy + bh * 0.5f) * inv;
    }
}

extern "C" __global__ __launch_bounds__(512, 4)
void spikefpn_fused(const float* __restrict__ x, const float* __restrict__ cw,
                    const float* __restrict__ gamma, const float* __restrict__ beta,
                    const float* __restrict__ cm, const float* __restrict__ vleak,
                    const float* __restrict__ tau, const float* __restrict__ erev,
                    const float* __restrict__ y3, const float* __restrict__ w3, const float* __restrict__ b3,
                    const float* __restrict__ y2, const float* __restrict__ w2, const float* __restrict__ b2,
                    const float* __restrict__ y1, const float* __restrict__ w1, const float* __restrict__ b1,
                    float* __restrict__ out, float* __restrict__ det)
{
    __shared__ float xs[NBUF * LDSF + 256];

    const int bid = blockIdx.x;
    const int tid = threadIdx.x;

    if (bid < NHEADB) {
        // ---------------- head path: wave-independent, no sync ----------------
        const int wid  = bid * 8 + (tid >> 6);   // 0..671
        const int lane = tid & 63;
        if (wid < 512) {
            head_wave<192, 64, 6>(y3, w3, b3, det, wid >> 6, wid & 63, lane,
                                  8.0f, 0, 10.f, 13.f, 16.f, 30.f, 33.f, 23.f);
        } else if (wid < 640) {
            const int sb = wid - 512;
            head_wave<384, 32, 5>(y2, w2, b2, det, sb >> 4, sb & 15, lane,
                                  16.0f, 12288, 30.f, 61.f, 62.f, 45.f, 59.f, 119.f);
        } else {
            const int sb = wid - 640;
            head_wave<768, 16, 4>(y1, w1, b1, det, sb >> 2, sb & 3, lane,
                                  32.0f, 15360, 116.f, 90.f, 156.f, 198.f, 373.f, 326.f);
        }
        return;
    }

    // ---------------- conv + LTC: global_load_lds, NBUF=2, counted waits ----------------
    const int cb = bid - NHEADB;
    const int bx = cb & 7;            // col tile 0..7
    const int by = (cb >> 3) & 31;    // row tile 0..31
    const int b  = cb >> 8;           // batch

    const int grow0 = by * CTH;
    const int gcol0 = bx * CTW;
    const size_t xb = (size_t)b * (TT * CC * HWp);

    // ---- per-thread staging meta (once). Every wave issues EXACTLY 4 loads/stage.
    int  goff[4];
    bool pred[4];
    uint32_t gbase[4];
    #pragma unroll
    for (int k = 0; k < 4; ++k) {
        const int g = tid + k * 512;
        const int wavebase = (tid & ~63) + k * 512;
        if (wavebase >= NG) {
            pred[k] = true;
            goff[k] = 0;
            gbase[k] = (uint32_t)SPARE_BYTES;
        } else {
            const bool valid = g < NG;
            const int gg  = valid ? g : 0;
            const int ch  = gg / (NROW * GCOL);
            const int rem = gg - ch * (NROW * GCOL);
            const int row = rem / GCOL;
            const int c4  = rem - row * GCOL;
            const int gr = grow0 + row - 1;
            const int gc = gcol0 - 4 + c4 * 4;
            const bool inb = valid && ((unsigned)gr < (unsigned)HH) && ((unsigned)gc < (unsigned)WW);
            pred[k] = inb;
            goff[k] = ch * HWp + gr * WW + gc;
            gbase[k] = (uint32_t)(wavebase * 16);   // wave-uniform LDS base
            if (valid && !inb) {
                float4 z = make_float4(0.f, 0.f, 0.f, 0.f);
                *(float4*)&xs[g * 4]        = z;
                *(float4*)&xs[LDSF + g * 4] = z;
            }
        }
    }

    lds_char_t* lds0 = (lds_char_t*)xs;

    auto issue_stage = [&](int t, int buf) {
        const float* xt = x + xb + (size_t)t * (CC * HWp);
        const uint32_t bufoff = (uint32_t)buf * (LDSF * 4);
        #pragma unroll
        for (int k = 0; k < 4; ++k) {
            if (pred[k]) {
                __builtin_amdgcn_global_load_lds(
                    (const __attribute__((address_space(1))) void*)(glb_char_t*)(const char*)(xt + goff[k]),
                    (__attribute__((address_space(3))) void*)(lds0 + bufoff + gbase[k]),
                    16, 0, 0);
            }
        }
    };

    // per-channel params (uniform -> SGPR)
    float g_[CC], be[CC], cmv[CC], vl[CC], tm[CC], er[CC];
    #pragma unroll
    for (int o = 0; o < CC; ++o) {
        g_[o] = gamma[o]; be[o] = beta[o]; cmv[o] = cm[o];
        vl[o] = vleak[o]; tm[o] = tau[o]; er[o] = erev[o];
    }

    const int tx = tid & 63;          // col 0..63
    const int r0 = (tid >> 6) * 2;    // rows r0, r0+1 (wave-uniform)

    // ---- prologue: stage t0 -> buf0, full drain (covers zero-fills too) ----
    issue_stage(0, 0);
    asm volatile("s_waitcnt vmcnt(0)" ::: "memory");
    asm volatile("s_waitcnt lgkmcnt(0)" ::: "memory");
    __builtin_amdgcn_s_barrier();
    __builtin_amdgcn_sched_barrier(0);

    v2f vpre[CC];   // .x = row r0, .y = row r0+1
    #pragma unroll
    for (int o = 0; o < CC; ++o) vpre[o] = (v2f){0.0f, 0.0f};

    #pragma unroll
    for (int t = 0; t < TT; ++t) {
        if (t + 1 < TT) issue_stage(t + 1, (t + 1) & 1);   // 1-deep prefetch

        const float* cur = xs + (t & 1) * LDSF;

        v2f acc[CC];
        #pragma unroll
        for (int o = 0; o < CC; ++o) acc[o] = (v2f){0.0f, 0.0f};

        #pragma unroll
        for (int ic = 0; ic < CC; ++ic) {
            // pairs (row r0+dr, row r0+dr+1) at cols tx..tx+2 -> ds_read2_b32 (72 dw apart)
            const float* lp = &cur[(ic * NROW + r0) * LCP + tx + 3];
            v2f xv[3][3];
            #pragma unroll
            for (int dr = 0; dr < 3; ++dr)
                #pragma unroll
                for (int dc = 0; dc < 3; ++dc)
                    xv[dr][dc] = (v2f){lp[dr * LCP + dc], lp[(dr + 1) * LCP + dc]};
            #pragma unroll
            for (int oc = 0; oc < CC; ++oc) {
                const float* wp = cw + (oc * CC + ic) * 9;   // uniform -> s_load (lgkmcnt)
                v2f a = acc[oc];
                #pragma unroll
                for (int dr = 0; dr < 3; ++dr)
                    #pragma unroll
                    for (int dc = 0; dc < 3; ++dc) {
                        const float w = wp[dr * 3 + dc];
                        a = __builtin_elementwise_fma((v2f){w, w}, xv[dr][dc], a);
                    }
                acc[oc] = a;
            }
        }

        // ---- LTC update + store (2 rows x 5 ch = 10 b32 stores, 256B/wave each) ----
        const size_t ob0 = (size_t)(grow0 + r0) * WW + gcol0 + tx;
        #pragma unroll
        for (int o = 0; o < CC; ++o) {
            float* op = out + ((size_t)((b * TT + t) * CC + o)) * HWp + ob0;

            float wih0 = fmaf(acc[o].x, g_[o], be[o]);
            float sg0  = fast_sigmoid(wih0);
            float den0 = fmaf(cmv[o], sg0, vl[o]);
            float num0 = fmaf(tm[o] * vpre[o].x, __builtin_amdgcn_rcpf(den0), wih0 * er[o]);
            float v0   = fast_sigmoid(num0);
            vpre[o].x = v0;
            op[0] = v0;

            float wih1 = fmaf(acc[o].y, g_[o], be[o]);
            float sg1  = fast_sigmoid(wih1);
            float den1 = fmaf(cmv[o], sg1, vl[o]);
            float num1 = fmaf(tm[o] * vpre[o].y, __builtin_amdgcn_rcpf(den1), wih1 * er[o]);
            float v1   = fast_sigmoid(num1);
            vpre[o].y = v1;
            op[WW] = v1;
        }

        // ---- counted wait: stores(t) are the 10 youngest; S(t+1) retired at vmcnt(10) ----
        if (t < TT - 1) {
            asm volatile("s_waitcnt vmcnt(10)" ::: "memory");
            __builtin_amdgcn_s_barrier();
            __builtin_amdgcn_sched_barrier(0);
        }
    }
}

extern "C" void kernel_launch(void* const* d_in, const int* in_sizes, int n_in,
                              void* d_out, int out_size, void* d_ws, size_t ws_size,
                              hipStream_t stream)
{
    const float* x     = (const float*)d_in[0];
    const float* y1    = (const float*)d_in[1];   // [8,768,16,16]
    const float* y2    = (const float*)d_in[2];   // [8,384,32,32]
    const float* y3    = (const float*)d_in[3];   // [8,192,64,64]
    const float* cw    = (const float*)d_in[4];
    const float* gamma = (const float*)d_in[5];
    const float* beta  = (const float*)d_in[6];
    const float* cm    = (const float*)d_in[7];
    const float* vleak = (const float*)d_in[8];
    const float* tau   = (const float*)d_in[9];
    const float* erev  = (const float*)d_in[10];
    const float* w1    = (const float*)d_in[11];
    const float* b1    = (const float*)d_in[12];
    const float* w2    = (const float*)d_in[13];
    const float* b2    = (const float*)d_in[14];
    const float* w3    = (const float*)d_in[15];
    const float* b3    = (const float*)d_in[16];

    float* out = (float*)d_out;
    float* det = out + (size_t)8 * TT * CC * HH * WW;   // 52,428,800

    spikefpn_fused<<<dim3(NHEADB + NCONVB), 512, 0, stream>>>(
        x, cw, gamma, beta, cm, vleak, tau, erev,
        y3, w3, b3, y2, w2, b2, y1, w1, b1, out, det);
}

// Round 12
// 139.139 us; speedup vs baseline: 2.3416x; 1.8782x over previous
//
#include <hip/hip_runtime.h>
#include <math.h>

#define HH 512
#define WW 512
#define HWp (HH * WW)
#define TT 5
#define CC 5

// conv tiling: 64 x 16 tile, 512 threads, 1 col x 2 adjacent rows per thread
#define CTW 64
#define CTH 16
#define NROW (CTH + 2)        // 18
#define GCOL 18               // 16B granules per padded row: cols [gcol0-4, gcol0+68)
#define LCP (GCOL * 4)        // 72 floats per padded row (granule g <-> byte g*16, linear)
#define LDSF (CC * NROW * LCP)   // 6480 floats = 25920 B per buffer
#define NG (CC * NROW * GCOL)    // 1620 granules
#define NBUF 3
#define SPARE_BYTES (NBUF * LDSF * 4)   // dump slot for dummy loads

#define NHEADB 672            // fast-head blocks (512 + 128 + 32), run first
#define NCONVB 2048           // 8 x 32 x 8

#define XS_FLOATS (NBUF * LDSF + 256)   // 19696 floats = 78784 B (head needs 18432 fl)

typedef float v2f __attribute__((ext_vector_type(2)));

typedef __attribute__((address_space(3))) char       lds_char_t;
typedef __attribute__((address_space(1)))  const char glb_char_t;

__device__ __forceinline__ float fast_sigmoid(float x) {
    return __builtin_amdgcn_rcpf(1.0f + __expf(-x));
}

extern "C" __global__ __launch_bounds__(512, 4)
void spikefpn_fused(const float* __restrict__ x, const float* __restrict__ cw,
                    const float* __restrict__ gamma, const float* __restrict__ beta,
                    const float* __restrict__ cm, const float* __restrict__ vleak,
                    const float* __restrict__ tau, const float* __restrict__ erev,
                    const float* __restrict__ y3, const float* __restrict__ w3, const float* __restrict__ b3,
                    const float* __restrict__ y2, const float* __restrict__ w2, const float* __restrict__ b2,
                    const float* __restrict__ y1, const float* __restrict__ w1, const float* __restrict__ b1,
                    float* __restrict__ out, float* __restrict__ det)
{
    __shared__ float xs[XS_FLOATS];

    const int bid = blockIdx.x;
    const int tid = threadIdx.x;

    if (bid < NHEADB) {
        // ---------------- FAST head path (r2 design): LDS wT + 8-way split ----------------
        float* smem = xs;
        const float *y, *w, *bias;
        int Cin, f, lgf, lgchunks, row_off;
        float s;
        float aw0, aw1, aw2, ah0, ah1, ah2;
        int sb;

        if (bid < 512) {
            sb = bid;       y = y3; w = w3; bias = b3; Cin = 192; f = 64; lgf = 6; lgchunks = 6; s = 8.0f;  row_off = 0;
            aw0 = 10.f;  ah0 = 13.f;  aw1 = 16.f;  ah1 = 30.f;  aw2 = 33.f;  ah2 = 23.f;
        } else if (bid < 640) {
            sb = bid - 512; y = y2; w = w2; bias = b2; Cin = 384; f = 32; lgf = 5; lgchunks = 4; s = 16.0f; row_off = 12288;
            aw0 = 30.f;  ah0 = 61.f;  aw1 = 62.f;  ah1 = 45.f;  aw2 = 59.f;  ah2 = 119.f;
        } else {
            sb = bid - 640; y = y1; w = w1; bias = b1; Cin = 768; f = 16; lgf = 4; lgchunks = 2; s = 32.0f; row_off = 15360;
            aw0 = 116.f; ah0 = 90.f;  aw1 = 156.f; ah1 = 198.f; aw2 = 373.f; ah2 = 326.f;
        }

        const int n     = f * f;
        const int b     = sb >> lgchunks;
        const int chunk = sb & ((1 << lgchunks) - 1);

        const int lane = tid & 63;
        const int grp  = tid >> 6;          // 0..7

        // stage wT (padded rows of 24) into LDS
        const int wtot = Cin * 21;
        for (int i = tid; i < wtot; i += 512) {
            int o = i / Cin;
            int c = i - o * Cin;
            smem[c * 24 + o] = w[i];
        }
        __syncthreads();

        const int G   = Cin >> 3;
        const int pix = (chunk << 6) + lane;

        float acc[21];
        #pragma unroll
        for (int o = 0; o < 21; ++o) acc[o] = 0.0f;

        const float* yp = y + ((size_t)b * Cin + (size_t)grp * G) * n + pix;
        const int wbase = grp * G * 24;

        #pragma unroll 4
        for (int c = 0; c < G; ++c) {
            float v = yp[(size_t)c * n];                     // coalesced
            const float* wr = &smem[wbase + c * 24];         // wave-uniform -> broadcast
            float4 q0 = *(const float4*)(wr);
            float4 q1 = *(const float4*)(wr + 4);
            float4 q2 = *(const float4*)(wr + 8);
            float4 q3 = *(const float4*)(wr + 12);
            float4 q4 = *(const float4*)(wr + 16);
            float  s20 = wr[20];
            float wv[21] = {q0.x,q0.y,q0.z,q0.w, q1.x,q1.y,q1.z,q1.w,
                            q2.x,q2.y,q2.z,q2.w, q3.x,q3.y,q3.z,q3.w,
                            q4.x,q4.y,q4.z,q4.w, s20};
            #pragma unroll
            for (int o = 0; o < 21; ++o) acc[o] = fmaf(v, wv[o], acc[o]);
        }
        __syncthreads();   // all reads of wT done; smem reused for reduction

        #pragma unroll
        for (int o = 0; o < 21; ++o) smem[tid * 21 + o] = acc[o];
        __syncthreads();

        if (tid < 64) {
            float r[21];
            #pragma unroll
            for (int o = 0; o < 21; ++o) r[o] = bias[o];
            #pragma unroll
            for (int g2 = 0; g2 < 8; ++g2) {
                const float* rp = &smem[(g2 * 64 + lane) * 21];
                #pragma unroll
                for (int o = 0; o < 21; ++o) r[o] += rp[o];
            }

            const int hy = pix >> lgf;
            const int hx = pix & (f - 1);
            const float inv = 1.0f / 512.0f;
            const float AW[3] = {aw0, aw1, aw2};
            const float AH[3] = {ah0, ah1, ah2};

            #pragma unroll
            for (int a = 0; a < 3; ++a) {
                const int row = row_off + pix * 3 + a;
                float* dp = det + ((size_t)b * 16128 + row) * 7;
                dp[0] = r[a];
                dp[1] = r[3 + a * 2];
                dp[2] = r[4 + a * 2];
                float cx = (fast_sigmoid(r[9  + a * 4]) + (float)hx) * s;
                float cy = (fast_sigmoid(r[10 + a * 4]) + (float)hy) * s;
                float bw = __expf(r[11 + a * 4]) * AW[a];
                float bh = __expf(r[12 + a * 4]) * AH[a];
                dp[3] = (cx - bw * 0.5f) * inv;
                dp[4] = (cy - bh * 0.5f) * inv;
                dp[5] = (cx + bw * 0.5f) * inv;
                dp[6] = (cy + bh * 0.5f) * inv;
            }
        }
        return;
    }

    // ---------------- conv + LTC: r9 verbatim (NBUF=3, counted waits, pk-FMA) ----------------
    const int cb = bid - NHEADB;
    const int bx = cb & 7;            // col tile 0..7
    const int by = (cb >> 3) & 31;    // row tile 0..31
    const int b  = cb >> 8;           // batch

    const int grow0 = by * CTH;
    const int gcol0 = bx * CTW;
    const size_t xb = (size_t)b * (TT * CC * HWp);

    // ---- per-thread staging meta (once). Every wave issues EXACTLY 4 loads/stage.
    int  goff[4];
    bool pred[4];
    uint32_t gbase[4];
    #pragma unroll
    for (int k = 0; k < 4; ++k) {
        const int g = tid + k * 512;
        const int wavebase = (tid & ~63) + k * 512;
        if (wavebase >= NG) {
            pred[k] = true;
            goff[k] = 0;
            gbase[k] = (uint32_t)SPARE_BYTES;
        } else {
            const bool valid = g < NG;
            const int gg  = valid ? g : 0;
            const int ch  = gg / (NROW * GCOL);
            const int rem = gg - ch * (NROW * GCOL);
            const int row = rem / GCOL;
            const int c4  = rem - row * GCOL;
            const int gr = grow0 + row - 1;
            const int gc = gcol0 - 4 + c4 * 4;
            const bool inb = valid && ((unsigned)gr < (unsigned)HH) && ((unsigned)gc < (unsigned)WW);
            pred[k] = inb;
            goff[k] = ch * HWp + gr * WW + gc;
            gbase[k] = (uint32_t)(wavebase * 16);   // wave-uniform LDS base
            if (valid && !inb) {
                float4 z = make_float4(0.f, 0.f, 0.f, 0.f);
                *(float4*)&xs[g * 4]            = z;
                *(float4*)&xs[LDSF + g * 4]     = z;
                *(float4*)&xs[2 * LDSF + g * 4] = z;
            }
        }
    }

    lds_char_t* lds0 = (lds_char_t*)xs;

    auto issue_stage = [&](int t, int buf) {
        const float* xt = x + xb + (size_t)t * (CC * HWp);
        const uint32_t bufoff = (uint32_t)buf * (LDSF * 4);
        #pragma unroll
        for (int k = 0; k < 4; ++k) {
            if (pred[k]) {
                __builtin_amdgcn_global_load_lds(
                    (const __attribute__((address_space(1))) void*)(glb_char_t*)(const char*)(xt + goff[k]),
                    (__attribute__((address_space(3))) void*)(lds0 + bufoff + gbase[k]),
                    16, 0, 0);
            }
        }
    };

    // per-channel params (uniform -> SGPR)
    float g_[CC], be[CC], cmv[CC], vl[CC], tm[CC], er[CC];
    #pragma unroll
    for (int o = 0; o < CC; ++o) {
        g_[o] = gamma[o]; be[o] = beta[o]; cmv[o] = cm[o];
        vl[o] = vleak[o]; tm[o] = tau[o]; er[o] = erev[o];
    }

    const int tx = tid & 63;          // col 0..63
    const int r0 = (tid >> 6) * 2;    // rows r0, r0+1 (wave-uniform)

    // ---- prologue: stage t0 -> buf0, t1 -> buf1; wait only t0 ----
    issue_stage(0, 0);
    issue_stage(1, 1);
    asm volatile("s_waitcnt vmcnt(4)" ::: "memory");
    asm volatile("s_waitcnt lgkmcnt(0)" ::: "memory");   // zero-fill writes visible
    __builtin_amdgcn_s_barrier();
    __builtin_amdgcn_sched_barrier(0);

    v2f vpre[CC];   // .x = row r0, .y = row r0+1
    #pragma unroll
    for (int o = 0; o < CC; ++o) vpre[o] = (v2f){0.0f, 0.0f};

    #pragma unroll
    for (int t = 0; t < TT; ++t) {
        if (t + 2 < TT) issue_stage(t + 2, (t + 2) % NBUF);   // 2-deep prefetch

        const float* cur = xs + (t % NBUF) * LDSF;

        v2f acc[CC];
        #pragma unroll
        for (int o = 0; o < CC; ++o) acc[o] = (v2f){0.0f, 0.0f};

        #pragma unroll
        for (int ic = 0; ic < CC; ++ic) {
            // pairs (row r0+dr, row r0+dr+1) at cols tx..tx+2 -> ds_read2_b32 (72 dw apart)
            const float* lp = &cur[(ic * NROW + r0) * LCP + tx + 3];
            v2f xv[3][3];
            #pragma unroll
            for (int dr = 0; dr < 3; ++dr)
                #pragma unroll
                for (int dc = 0; dc < 3; ++dc)
                    xv[dr][dc] = (v2f){lp[dr * LCP + dc], lp[(dr + 1) * LCP + dc]};
            #pragma unroll
            for (int oc = 0; oc < CC; ++oc) {
                const float* wp = cw + (oc * CC + ic) * 9;   // uniform -> s_load (lgkmcnt)
                v2f a = acc[oc];
                #pragma unroll
                for (int dr = 0; dr < 3; ++dr)
                    #pragma unroll
                    for (int dc = 0; dc < 3; ++dc) {
                        const float w = wp[dr * 3 + dc];
                        a = __builtin_elementwise_fma((v2f){w, w}, xv[dr][dc], a);
                    }
                acc[oc] = a;
            }
        }

        // ---- LTC update + store (2 rows x 5 ch = 10 b32 stores, 256B/wave each) ----
        const size_t ob0 = (size_t)(grow0 + r0) * WW + gcol0 + tx;
        #pragma unroll
        for (int o = 0; o < CC; ++o) {
            float* op = out + ((size_t)((b * TT + t) * CC + o)) * HWp + ob0;

            float wih0 = fmaf(acc[o].x, g_[o], be[o]);
            float sg0  = fast_sigmoid(wih0);
            float den0 = fmaf(cmv[o], sg0, vl[o]);
            float num0 = fmaf(tm[o] * vpre[o].x, __builtin_amdgcn_rcpf(den0), wih0 * er[o]);
            float v0   = fast_sigmoid(num0);
            vpre[o].x = v0;
            op[0] = v0;

            float wih1 = fmaf(acc[o].y, g_[o], be[o]);
            float sg1  = fast_sigmoid(wih1);
            float den1 = fmaf(cmv[o], sg1, vl[o]);
            float num1 = fmaf(tm[o] * vpre[o].y, __builtin_amdgcn_rcpf(den1), wih1 * er[o]);
            float v1   = fast_sigmoid(num1);
            vpre[o].y = v1;
            op[WW] = v1;
        }

        // ---- counted waits: keep next-next loads in flight across the barrier ----
        if (t <= 2) {
            // FIFO: S(t+1):4 | stores(t-1):10 | S(t+2):4 | stores(t):10 -> 14 youngest stay
            asm volatile("s_waitcnt vmcnt(14)" ::: "memory");
            __builtin_amdgcn_s_barrier();
            __builtin_amdgcn_sched_barrier(0);
        } else if (t == 3) {
            asm volatile("s_waitcnt vmcnt(10)" ::: "memory");
            __builtin_amdgcn_s_barrier();
            __builtin_amdgcn_sched_barrier(0);
        }
    }
}

extern "C" void kernel_launch(void* const* d_in, const int* in_sizes, int n_in,
                              void* d_out, int out_size, void* d_ws, size_t ws_size,
                              hipStream_t stream)
{
    const float* x     = (const float*)d_in[0];
    const float* y1    = (const float*)d_in[1];   // [8,768,16,16]
    const float* y2    = (const float*)d_in[2];   // [8,384,32,32]
    const float* y3    = (const float*)d_in[3];   // [8,192,64,64]
    const float* cw    = (const float*)d_in[4];
    const float* gamma = (const float*)d_in[5];
    const float* beta  = (const float*)d_in[6];
    const float* cm    = (const float*)d_in[7];
    const float* vleak = (const float*)d_in[8];
    const float* tau   = (const float*)d_in[9];
    const float* erev  = (const float*)d_in[10];
    const float* w1    = (const float*)d_in[11];
    const float* b1    = (const float*)d_in[12];
    const float* w2    = (const float*)d_in[13];
    const float* b2    = (const float*)d_in[14];
    const float* w3    = (const float*)d_in[15];
    const float* b3    = (const float*)d_in[16];

    float* out = (float*)d_out;
    float* det = out + (size_t)8 * TT * CC * HH * WW;   // 52,428,800

    spikefpn_fused<<<dim3(NHEADB + NCONVB), 512, 0, stream>>>(
        x, cw, gamma, beta, cm, vleak, tau, erev,
        y3, w3, b3, y2, w2, b2, y1, w1, b1, out, det);
}